// Round 11
// baseline (158.594 us; speedup 1.0000x reference)
//
#include <hip/hip_runtime.h>
#include <math.h>

#define BB 8
#define QQ 100
#define CC 41
#define TT 50
#define PP 12544        // = 49 * 256
#define QP 112          // padded Q rows (7 * 16)
#define TP 64           // padded T rows (4 * 16)
#define KS 8            // split-K over P
#define KCH (PP / KS)   // 1568
#define NT (BB * TT)    // 400
#define NMASK (NT + BB * QQ)   // 1200
#define NBIN 16         // 16-row sort bins
#define NCH 8           // 32-row sample chunks (2 bins each)
#define CROWS 33        // staged rows per chunk (32 + 1 halo)

typedef _Float16 f16x8 __attribute__((ext_vector_type(8)));
typedef float f32x4 __attribute__((ext_vector_type(4)));

// ---------------------------------------------------------------------------
// sort_kernel: block (b,bin) of 256 thr; 16 bins of 16 rows. Deterministic
// ballot-scan counting sort. Emits chunk-local gather entries (chunk = bin>>1,
// 32 rows + halo):
//   t.x=(r0-32*(bin>>1))*256+xb  t.y=(r1-...)*256+xb
//   t.z=(wa,wb) f16x2 x-weights  t.w=(ya,yb) f16x2 y-weights (border-folded)
// binStart[b*17 + 0..16].
// ---------------------------------------------------------------------------
__global__ __launch_bounds__(256) void sort_kernel(
    const float* __restrict__ coords, uint4* __restrict__ stb,
    int* __restrict__ binStart)
{
    int b = blockIdx.x >> 4;
    int mybin = blockIdx.x & 15;
    int tid = threadIdx.x;
    int lane = tid & 63, w = tid >> 6;
    const float2* cd = (const float2*)coords + (size_t)b * PP;
    __shared__ int hist[NBIN];
    __shared__ int woff[4];
    __shared__ int running;
    if (tid < NBIN) hist[tid] = 0;
    __syncthreads();
    for (int p = tid; p < PP; p += 256) {
        float y = fmaf(cd[p].y, 256.f, -0.5f);
        int y0 = (int)floorf(y);
        int bin = min(max(y0, 0), 255) >> 4;
        atomicAdd(&hist[bin], 1);
    }
    __syncthreads();
    int start = 0;
    for (int i = 0; i < mybin; ++i) start += hist[i];
    if (tid == 0) {
        running = 0;
        binStart[b * 17 + mybin] = start;
        if (mybin == 15) binStart[b * 17 + 16] = PP;
    }
    __syncthreads();

    uint4* out = stb + (size_t)b * PP;
    for (int c = 0; c < 49; ++c) {
        int p = c * 256 + tid;
        float2 cc = cd[p];
        float x = fmaf(cc.x, 256.f, -0.5f);
        float y = fmaf(cc.y, 256.f, -0.5f);
        float x0f = floorf(x), y0f = floorf(y);
        int x0 = (int)x0f, y0 = (int)y0f;
        int bin = min(max(y0, 0), 255) >> 4;
        bool match = (bin == mybin);
        unsigned long long bal = __ballot(match);
        if (lane == 0) woff[w] = (int)__popcll(bal);
        __syncthreads();
        int wbase = 0;
        #pragma unroll
        for (int i = 0; i < 4; ++i) if (i < w) wbase += woff[i];
        int tot = woff[0] + woff[1] + woff[2] + woff[3];
        if (match) {
            int rk = (int)__popcll(bal & ((1ull << lane) - 1ull));
            float wx = x - x0f, wy = y - y0f;
            int xb = min(max(x0, 0), 254);
            int r0 = min(max(y0, 0), 255);
            int r1 = min(y0 + 1, 255);
            int base = (mybin >> 1) * 32;
            float wa, wb;
            if (x0 < 0)        { wa = wx;       wb = 0.f; }
            else if (x0 > 254) { wa = 0.f;      wb = 1.f - wx; }
            else               { wa = 1.f - wx; wb = wx; }
            float ya = (y0 >= 0)  ? 1.f - wy : 0.f;
            float yb = (y0 < 255) ? wy       : 0.f;
            union { unsigned int u; _Float16 h[2]; } pw, pyw;
            pw.h[0] = (_Float16)wa;  pw.h[1] = (_Float16)wb;
            pyw.h[0] = (_Float16)ya; pyw.h[1] = (_Float16)yb;
            uint4 t;
            t.x = (unsigned int)((r0 - base) * 256 + xb);
            t.y = (unsigned int)((r1 - base) * 256 + xb);
            t.z = pw.u; t.w = pyw.u;
            out[start + running + wbase + rk] = t;
        }
        __syncthreads();
        if (tid == 0) running += tot;
        __syncthreads();
    }
}

// ---------------------------------------------------------------------------
// sample_kernel: block (mask, chunk) of 512 thr — 9600 short blocks.
// Stage 33 fp32 rows (33.8 KB -> 4 blocks/CU), sample this chunk's sorted
// points from LDS, write per-(mask,chunk) partial sums (no atomics).
// ---------------------------------------------------------------------------
__global__ __launch_bounds__(512, 8) void sample_kernel(
    const float* __restrict__ tgt_masks, const float* __restrict__ pred_masks,
    const uint4* __restrict__ stb, const int* __restrict__ binStart,
    _Float16* __restrict__ tm, _Float16* __restrict__ om, _Float16* __restrict__ sg,
    float* __restrict__ psum)
{
    __shared__ float buf[CROWS * 256];    // 33,792 B
    __shared__ float red[8], red2[8];
    int bid = blockIdx.x;
    int id = bid >> 3;
    int c = bid & 7;
    int tid = threadIdx.x;
    bool is_t = id < NT;
    int b;
    const float* m;
    _Float16* dst;
    _Float16* dsg = nullptr;
    if (is_t) {
        b = id / TT;
        m = tgt_masks + (size_t)id * 65536;
        dst = tm + ((size_t)b * TP + (id % TT)) * PP;
    } else {
        int bq = id - NT;
        b = bq / QQ;
        m = pred_masks + (size_t)bq * 65536;
        dst = om + ((size_t)b * QP + (bq % QQ)) * PP;
        dsg = sg + ((size_t)b * QP + (bq % QQ)) * PP;
    }

    // ---- stage rows [32c, 32c+33) (clamped) ----
    {
        int rows = min(CROWS, 256 - 32 * c);
        int nv4 = rows * 64;                     // uint4 count
        const uint4* src = (const uint4*)(m + 32 * c * 256);
        uint4* dl = (uint4*)buf;
        #pragma unroll
        for (int j = 0; j < 5; ++j) {
            int idx = j * 512 + tid;
            if (idx < nv4) dl[idx] = src[idx];
        }
    }
    __syncthreads();

    const uint4* tb = stb + (size_t)b * PP;
    const int* bs = binStart + b * 17;
    int ps = bs[2 * c], pe = bs[2 * c + 2];

    float l1 = 0.f, l2 = 0.f;
    for (int p = ps + tid; p < pe; p += 512) {
        uint4 t = tb[p];
        float v00 = buf[t.x], v01 = buf[t.x + 1];
        float v10 = buf[t.y], v11 = buf[t.y + 1];
        union { unsigned int u; _Float16 h[2]; } pw, pyw;
        pw.u = t.z; pyw.u = t.w;
        float wa = (float)pw.h[0], wb = (float)pw.h[1];
        float ya = (float)pyw.h[0], yb = (float)pyw.h[1];
        float v = ya * fmaf(wa, v00, wb * v01) + yb * fmaf(wa, v10, wb * v11);
        dst[p] = (_Float16)v;
        if (is_t) {
            l1 += v;
        } else {
            float e = __expf(-fabsf(v));
            float q = 1.f / (1.f + e);
            float g = (v >= 0.f) ? q : e * q;
            dsg[p] = (_Float16)g;
            l1 += fmaxf(v, 0.f) + __logf(1.f + e);
            l2 += g;
        }
    }

    #pragma unroll
    for (int off = 32; off; off >>= 1) {
        l1 += __shfl_down(l1, off, 64);
        l2 += __shfl_down(l2, off, 64);
    }
    if ((tid & 63) == 0) { red[tid >> 6] = l1; red2[tid >> 6] = l2; }
    __syncthreads();
    if (tid == 0) {
        float t1 = 0.f, t2 = 0.f;
        #pragma unroll
        for (int w = 0; w < 8; ++w) { t1 += red[w]; t2 += red2[w]; }
        psum[(size_t)bid * 2] = t1;
        psum[(size_t)bid * 2 + 1] = t2;
    }
}

// grid (7 qt, 8 b, KS). 4 waves; wave w owns t-tile w. C1=om.tm^T, C2=sig.tm^T.
__global__ __launch_bounds__(256) void dot_mfma_kernel(
    const _Float16* __restrict__ om, const _Float16* __restrict__ sg,
    const _Float16* __restrict__ tm,
    float* __restrict__ part_om, float* __restrict__ part_s)
{
    int qt = blockIdx.x, b = blockIdx.y, ks = blockIdx.z;
    int tid = threadIdx.x, lane = tid & 63, w = tid >> 6;
    int ra = lane & 15;
    int ko = (lane >> 4) * 8;
    const _Float16* pa = om + ((size_t)(b * QP + qt * 16 + ra)) * PP + ks * KCH + ko;
    const _Float16* ps = sg + ((size_t)(b * QP + qt * 16 + ra)) * PP + ks * KCH + ko;
    const _Float16* pb = tm + ((size_t)(b * TP + w * 16 + ra)) * PP + ks * KCH + ko;
    f32x4 accO = {0.f, 0.f, 0.f, 0.f};
    f32x4 accS = {0.f, 0.f, 0.f, 0.f};
    #pragma unroll 7
    for (int k = 0; k < KCH / 32; ++k) {
        f16x8 a = *(const f16x8*)(pa + (size_t)k * 32);
        f16x8 s = *(const f16x8*)(ps + (size_t)k * 32);
        f16x8 bb = *(const f16x8*)(pb + (size_t)k * 32);
        accO = __builtin_amdgcn_mfma_f32_16x16x32_f16(a, bb, accO, 0, 0, 0);
        accS = __builtin_amdgcn_mfma_f32_16x16x32_f16(s, bb, accS, 0, 0, 0);
    }
    int t = w * 16 + ra;
    int q = qt * 16 + (lane >> 4) * 4;
    size_t bse = (((size_t)ks * BB + b) * QP + q) * TP + t;
    #pragma unroll
    for (int r = 0; r < 4; ++r) {
        part_om[bse + (size_t)r * TP] = accO[r];
        part_s[bse + (size_t)r * TP] = accS[r];
    }
}

__global__ __launch_bounds__(256) void epilogue_kernel(
    const float* __restrict__ part_om, const float* __restrict__ part_s,
    const float* __restrict__ psum, const float* __restrict__ pred_logits,
    const float* __restrict__ pred_obj, const int* __restrict__ labels,
    float* __restrict__ out)
{
    int i = blockIdx.x * 256 + threadIdx.x;
    if (i >= BB * QQ * TT) return;
    int t = i % TT;
    int bq = i / TT;
    int b = bq / QQ, q = bq % QQ;
    float dO = 0.f, dS = 0.f;
    #pragma unroll
    for (int ks = 0; ks < KS; ++ks) {
        size_t o = (((size_t)ks * BB + b) * QP + q) * TP + t;
        dO += part_om[o];
        dS += part_s[o];
    }
    int omid = NT + bq;
    int tmid = b * TT + t;
    float ns = 0.f, ss = 0.f, ts = 0.f;
    #pragma unroll
    for (int j = 0; j < NCH; ++j) {
        ns += psum[(size_t)(omid * NCH + j) * 2];
        ss += psum[(size_t)(omid * NCH + j) * 2 + 1];
        ts += psum[(size_t)(tmid * NCH + j) * 2];
    }
    float cmask = (ns - dO) * (1.f / PP);
    float cdice = 1.f - (2.f * dS + 1.f) / (ss + ts + 1.f);
    int label = labels[b * TT + t];
    float a0 = pred_obj[bq * 2], a1 = pred_obj[bq * 2 + 1];
    float prob;
    if (label == CC - 1) {
        prob = 1.f / (1.f + __expf(a0 - a1));
    } else {
        float pc = 1.f / (1.f + __expf(-pred_logits[(size_t)bq * CC + label]));
        float po = 1.f / (1.f + __expf(a1 - a0));
        prob = sqrtf(pc * po);
    }
    out[i] = 5.f * cmask - 2.f * prob + 5.f * cdice;
}

extern "C" void kernel_launch(void* const* d_in, const int* in_sizes, int n_in,
                              void* d_out, int out_size, void* d_ws, size_t ws_size,
                              hipStream_t stream) {
    const float* pred_logits = (const float*)d_in[0];
    const float* pred_obj    = (const float*)d_in[1];
    const float* pred_masks  = (const float*)d_in[2];
    const float* tgt_masks   = (const float*)d_in[3];
    const int*   tgt_labels  = (const int*)d_in[4];
    const float* coords      = (const float*)d_in[5];
    float* out = (float*)d_out;

    char* ws = (char*)d_ws;
    const size_t SZ_TB = (size_t)BB * PP * 16;           // 1,605,632
    const size_t SZ_BS = 1024;                           // binStart (544 B used)
    const size_t SZ_OM = (size_t)BB * QP * PP * 2;       // 22,478,848
    const size_t SZ_TM = (size_t)BB * TP * PP * 2;       // 12,845,056
    const size_t SZ_PT = (size_t)KS * BB * QP * TP * 4;  // 1,835,008
    uint4* stb    = (uint4*)ws;
    int* binStart = (int*)(ws + SZ_TB);
    _Float16* om  = (_Float16*)(ws + SZ_TB + SZ_BS);
    _Float16* sg  = (_Float16*)(ws + SZ_TB + SZ_BS + SZ_OM);
    _Float16* tmm = (_Float16*)(ws + SZ_TB + SZ_BS + 2 * SZ_OM);
    float* part_om = (float*)(ws + SZ_TB + SZ_BS + 2 * SZ_OM + SZ_TM);
    float* part_s  = (float*)(ws + SZ_TB + SZ_BS + 2 * SZ_OM + SZ_TM + SZ_PT);
    float* psum    = (float*)(ws + SZ_TB + SZ_BS + 2 * SZ_OM + SZ_TM + 2 * SZ_PT);

    hipLaunchKernelGGL(sort_kernel, dim3(BB * NBIN), dim3(256), 0, stream,
                       coords, stb, binStart);
    hipLaunchKernelGGL(sample_kernel, dim3(NMASK * NCH), dim3(512), 0, stream,
                       tgt_masks, pred_masks, stb, binStart, tmm, om, sg, psum);
    hipLaunchKernelGGL(dot_mfma_kernel, dim3(QP / 16, BB, KS), dim3(256), 0, stream,
                       om, sg, tmm, part_om, part_s);
    hipLaunchKernelGGL(epilogue_kernel, dim3((BB * QQ * TT + 255) / 256), dim3(256),
                       0, stream,
                       part_om, part_s, psum, pred_logits, pred_obj,
                       tgt_labels, out);
}

// Round 12
// 148.454 us; speedup vs baseline: 1.0683x; 1.0683x over previous
//
#include <hip/hip_runtime.h>
#include <math.h>

#define BB 8
#define QQ 100
#define CC 41
#define TT 50
#define PP 12544        // = 49 * 256
#define QP 112          // padded Q rows (7 * 16)
#define TP 64           // padded T rows (4 * 16)
#define KS 8            // split-K over P
#define KCH (PP / KS)   // 1568
#define NT (BB * TT)    // 400
#define NMASK (NT + BB * QQ)   // 1200
#define NCHK 16         // 16-row chunks per mask
#define RING 4          // ring depth (chunks)

typedef _Float16 f16x8 __attribute__((ext_vector_type(8)));
typedef float f32x4 __attribute__((ext_vector_type(4)));

#if defined(__has_builtin)
#if __has_builtin(__builtin_amdgcn_global_load_lds)
#define HAVE_GLL 1
#endif
#endif

// ---------------------------------------------------------------------------
// sort_kernel: one block per batch. Two-pass LDS-atomic counting sort of the
// batch's points into 16 16-row bins. Slot order within a bin is
// non-deterministic, but all consumers are permutation-invariant.
// Entry: t.x/t.y = RING-GLOBAL float indices of (r0,xb)/(r1,xb);
//        t.z = (wa,wb) f16x2 x-weights; t.w = (ya,yb) f16x2 y-weights.
// ---------------------------------------------------------------------------
__global__ __launch_bounds__(1024) void sort_kernel(
    const float* __restrict__ coords, uint4* __restrict__ stb,
    int* __restrict__ binStart)
{
    int b = blockIdx.x;
    int tid = threadIdx.x;
    const float2* cd = (const float2*)coords + (size_t)b * PP;
    __shared__ int hist[16];
    __shared__ int cur[16];
    if (tid < 16) hist[tid] = 0;
    __syncthreads();
    for (int p = tid; p < PP; p += 1024) {
        float y = fmaf(cd[p].y, 256.f, -0.5f);
        int bin = min(max((int)floorf(y), 0), 255) >> 4;
        atomicAdd(&hist[bin], 1);
    }
    __syncthreads();
    if (tid == 0) {
        int acc = 0;
        for (int i = 0; i < 16; ++i) {
            cur[i] = acc;
            binStart[b * 17 + i] = acc;
            acc += hist[i];
        }
        binStart[b * 17 + 16] = PP;
    }
    __syncthreads();
    uint4* out = stb + (size_t)b * PP;
    for (int p = tid; p < PP; p += 1024) {
        float2 cc = cd[p];
        float x = fmaf(cc.x, 256.f, -0.5f);
        float y = fmaf(cc.y, 256.f, -0.5f);
        float x0f = floorf(x), y0f = floorf(y);
        int x0 = (int)x0f, y0 = (int)y0f;
        int bin = min(max(y0, 0), 255) >> 4;
        float wx = x - x0f, wy = y - y0f;
        int xb = min(max(x0, 0), 254);
        int r0 = min(max(y0, 0), 255);
        int r1 = min(y0 + 1, 255);
        float wa, wb;
        if (x0 < 0)        { wa = wx;       wb = 0.f; }
        else if (x0 > 254) { wa = 0.f;      wb = 1.f - wx; }
        else               { wa = 1.f - wx; wb = wx; }
        float ya = (y0 >= 0)  ? 1.f - wy : 0.f;
        float yb = (y0 < 255) ? wy       : 0.f;
        union { unsigned int u; _Float16 h[2]; } pw, pyw;
        pw.h[0] = (_Float16)wa;  pw.h[1] = (_Float16)wb;
        pyw.h[0] = (_Float16)ya; pyw.h[1] = (_Float16)yb;
        uint4 t;
        t.x = (unsigned int)(((r0 >> 4) & 3) * 4096 + (r0 & 15) * 256 + xb);
        t.y = (unsigned int)(((r1 >> 4) & 3) * 4096 + (r1 & 15) * 256 + xb);
        t.z = pw.u; t.w = pyw.u;
        int slot = atomicAdd(&cur[bin], 1);
        out[slot] = t;
    }
}

// ---------------------------------------------------------------------------
// sample_kernel: one block (1024 thr) per mask. 16-row chunks streamed via
// async global_load_lds into a 4-deep LDS ring; counted vmcnt (never 0 in the
// steady loop) + raw s_barrier keep 2-3 chunk DMAs in flight across barriers.
// Sample phase gathers from the ring at ring-global addresses (halo = next
// ring slot, already resident).
// ---------------------------------------------------------------------------
__global__ __launch_bounds__(1024) void sample_kernel(
    const float* __restrict__ tgt_masks, const float* __restrict__ pred_masks,
    const uint4* __restrict__ stb, const int* __restrict__ binStart,
    _Float16* __restrict__ tm, _Float16* __restrict__ om, _Float16* __restrict__ sg,
    float* __restrict__ tmsum, float* __restrict__ nsum, float* __restrict__ ssum)
{
    __shared__ float ring[RING][NCHK * 256];   // 65,536 B
    __shared__ float red[16], red2[16];
    int id = blockIdx.x;
    int tid = threadIdx.x;
    bool is_t = id < NT;
    int b;
    const float* m;
    _Float16* dst;
    _Float16* dsg = nullptr;
    if (is_t) {
        b = id / TT;
        m = tgt_masks + (size_t)id * 65536;
        dst = tm + ((size_t)b * TP + (id % TT)) * PP;
    } else {
        int bq = id - NT;
        b = bq / QQ;
        m = pred_masks + (size_t)bq * 65536;
        dst = om + ((size_t)b * QP + (bq % QQ)) * PP;
        dsg = sg + ((size_t)b * QP + (bq % QQ)) * PP;
    }
    const uint4* tb = stb + (size_t)b * PP;
    const int* bs = binStart + b * 17;
    const float* base = &ring[0][0];

    // issue one chunk's DMA: 1024 thr x 16 B = 16 KB = 16 rows, 1 instr/wave
    auto issue = [&](int c) {
        const float* g = m + c * 4096 + tid * 4;
        float* l = &ring[c & 3][tid * 4];
#ifdef HAVE_GLL
        __builtin_amdgcn_global_load_lds(
            (const __attribute__((address_space(1))) unsigned int*)g,
            (__attribute__((address_space(3))) unsigned int*)l, 16, 0, 0);
#else
        *(uint4*)l = *(const uint4*)g;
#endif
    };

    issue(0); issue(1); issue(2);

    float l1 = 0.f, l2 = 0.f;
    for (int c = 0; c < NCHK; ++c) {
        // chunk c+1 (halo) must be resident; DMA(c+2) is always younger, so
        // vmcnt(1) suffices while c+2 exists; drain at the tail.
        if (c < NCHK - 2) asm volatile("s_waitcnt vmcnt(1) lgkmcnt(0)" ::: "memory");
        else              asm volatile("s_waitcnt vmcnt(0) lgkmcnt(0)" ::: "memory");
        __builtin_amdgcn_s_barrier();       // raw barrier: no vmcnt(0) drain
        if (c + 3 < NCHK) issue(c + 3);     // overwrites slot of chunk c-1 (done)

        int pe = bs[c + 1];
        for (int p = bs[c] + tid; p < pe; p += 1024) {
            uint4 t = tb[p];
            float v00 = base[t.x], v01 = base[t.x + 1];
            float v10 = base[t.y], v11 = base[t.y + 1];
            union { unsigned int u; _Float16 h[2]; } pw, pyw;
            pw.u = t.z; pyw.u = t.w;
            float wa = (float)pw.h[0], wb = (float)pw.h[1];
            float ya = (float)pyw.h[0], yb = (float)pyw.h[1];
            float v = ya * fmaf(wa, v00, wb * v01) + yb * fmaf(wa, v10, wb * v11);
            dst[p] = (_Float16)v;
            if (is_t) {
                l1 += v;
            } else {
                float e = __expf(-fabsf(v));
                float q = 1.f / (1.f + e);
                float g = (v >= 0.f) ? q : e * q;
                dsg[p] = (_Float16)g;
                l1 += fmaxf(v, 0.f) + __logf(1.f + e);
                l2 += g;
            }
        }
    }

    #pragma unroll
    for (int off = 32; off; off >>= 1) {
        l1 += __shfl_down(l1, off, 64);
        l2 += __shfl_down(l2, off, 64);
    }
    if ((tid & 63) == 0) { red[tid >> 6] = l1; red2[tid >> 6] = l2; }
    __syncthreads();
    if (tid == 0) {
        float t1 = 0.f, t2 = 0.f;
        #pragma unroll
        for (int w = 0; w < 16; ++w) { t1 += red[w]; t2 += red2[w]; }
        if (is_t) tmsum[id] = t1;
        else { nsum[id - NT] = t1; ssum[id - NT] = t2; }
    }
}

// grid (7 qt, 8 b, KS). 4 waves; wave w owns t-tile w. C1=om.tm^T, C2=sig.tm^T.
__global__ __launch_bounds__(256) void dot_mfma_kernel(
    const _Float16* __restrict__ om, const _Float16* __restrict__ sg,
    const _Float16* __restrict__ tm,
    float* __restrict__ part_om, float* __restrict__ part_s)
{
    int qt = blockIdx.x, b = blockIdx.y, ks = blockIdx.z;
    int tid = threadIdx.x, lane = tid & 63, w = tid >> 6;
    int ra = lane & 15;
    int ko = (lane >> 4) * 8;
    const _Float16* pa = om + ((size_t)(b * QP + qt * 16 + ra)) * PP + ks * KCH + ko;
    const _Float16* ps = sg + ((size_t)(b * QP + qt * 16 + ra)) * PP + ks * KCH + ko;
    const _Float16* pb = tm + ((size_t)(b * TP + w * 16 + ra)) * PP + ks * KCH + ko;
    f32x4 accO = {0.f, 0.f, 0.f, 0.f};
    f32x4 accS = {0.f, 0.f, 0.f, 0.f};
    #pragma unroll 7
    for (int k = 0; k < KCH / 32; ++k) {
        f16x8 a = *(const f16x8*)(pa + (size_t)k * 32);
        f16x8 s = *(const f16x8*)(ps + (size_t)k * 32);
        f16x8 bb = *(const f16x8*)(pb + (size_t)k * 32);
        accO = __builtin_amdgcn_mfma_f32_16x16x32_f16(a, bb, accO, 0, 0, 0);
        accS = __builtin_amdgcn_mfma_f32_16x16x32_f16(s, bb, accS, 0, 0, 0);
    }
    int t = w * 16 + ra;
    int q = qt * 16 + (lane >> 4) * 4;
    size_t bse = (((size_t)ks * BB + b) * QP + q) * TP + t;
    #pragma unroll
    for (int r = 0; r < 4; ++r) {
        part_om[bse + (size_t)r * TP] = accO[r];
        part_s[bse + (size_t)r * TP] = accS[r];
    }
}

__global__ __launch_bounds__(256) void epilogue_kernel(
    const float* __restrict__ part_om, const float* __restrict__ part_s,
    const float* __restrict__ tmsum, const float* __restrict__ nsum,
    const float* __restrict__ ssum, const float* __restrict__ pred_logits,
    const float* __restrict__ pred_obj, const int* __restrict__ labels,
    float* __restrict__ out)
{
    int i = blockIdx.x * 256 + threadIdx.x;
    if (i >= BB * QQ * TT) return;
    int t = i % TT;
    int bq = i / TT;
    int b = bq / QQ, q = bq % QQ;
    float dO = 0.f, dS = 0.f;
    #pragma unroll
    for (int ks = 0; ks < KS; ++ks) {
        size_t o = (((size_t)ks * BB + b) * QP + q) * TP + t;
        dO += part_om[o];
        dS += part_s[o];
    }
    float ns = nsum[bq], ss = ssum[bq];
    float ts = tmsum[b * TT + t];
    float cmask = (ns - dO) * (1.f / PP);
    float cdice = 1.f - (2.f * dS + 1.f) / (ss + ts + 1.f);
    int label = labels[b * TT + t];
    float a0 = pred_obj[bq * 2], a1 = pred_obj[bq * 2 + 1];
    float prob;
    if (label == CC - 1) {
        prob = 1.f / (1.f + __expf(a0 - a1));
    } else {
        float pc = 1.f / (1.f + __expf(-pred_logits[(size_t)bq * CC + label]));
        float po = 1.f / (1.f + __expf(a1 - a0));
        prob = sqrtf(pc * po);
    }
    out[i] = 5.f * cmask - 2.f * prob + 5.f * cdice;
}

extern "C" void kernel_launch(void* const* d_in, const int* in_sizes, int n_in,
                              void* d_out, int out_size, void* d_ws, size_t ws_size,
                              hipStream_t stream) {
    const float* pred_logits = (const float*)d_in[0];
    const float* pred_obj    = (const float*)d_in[1];
    const float* pred_masks  = (const float*)d_in[2];
    const float* tgt_masks   = (const float*)d_in[3];
    const int*   tgt_labels  = (const int*)d_in[4];
    const float* coords      = (const float*)d_in[5];
    float* out = (float*)d_out;

    char* ws = (char*)d_ws;
    const size_t SZ_TB = (size_t)BB * PP * 16;           // 1,605,632
    const size_t SZ_BS = 1024;
    const size_t SZ_OM = (size_t)BB * QP * PP * 2;       // 22,478,848
    const size_t SZ_TM = (size_t)BB * TP * PP * 2;       // 12,845,056
    const size_t SZ_PT = (size_t)KS * BB * QP * TP * 4;  // 1,835,008
    uint4* stb    = (uint4*)ws;
    int* binStart = (int*)(ws + SZ_TB);
    _Float16* om  = (_Float16*)(ws + SZ_TB + SZ_BS);
    _Float16* sg  = (_Float16*)(ws + SZ_TB + SZ_BS + SZ_OM);
    _Float16* tmm = (_Float16*)(ws + SZ_TB + SZ_BS + 2 * SZ_OM);
    float* part_om = (float*)(ws + SZ_TB + SZ_BS + 2 * SZ_OM + SZ_TM);
    float* part_s  = (float*)(ws + SZ_TB + SZ_BS + 2 * SZ_OM + SZ_TM + SZ_PT);
    float* tmsum   = (float*)(ws + SZ_TB + SZ_BS + 2 * SZ_OM + SZ_TM + 2 * SZ_PT);
    float* nsum    = tmsum + BB * TT;
    float* ssum    = nsum + BB * QQ;

    hipLaunchKernelGGL(sort_kernel, dim3(BB), dim3(1024), 0, stream,
                       coords, stb, binStart);
    hipLaunchKernelGGL(sample_kernel, dim3(NMASK), dim3(1024), 0, stream,
                       tgt_masks, pred_masks, stb, binStart,
                       tmm, om, sg, tmsum, nsum, ssum);
    hipLaunchKernelGGL(dot_mfma_kernel, dim3(QP / 16, BB, KS), dim3(256), 0, stream,
                       om, sg, tmm, part_om, part_s);
    hipLaunchKernelGGL(epilogue_kernel, dim3((BB * QQ * TT + 255) / 256), dim3(256),
                       0, stream,
                       part_om, part_s, tmsum, nsum, ssum,
                       pred_logits, pred_obj, tgt_labels, out);
}